// Round 1
// baseline (3703.219 us; speedup 1.0000x reference)
//
#include <hip/hip_runtime.h>

#define LQ 2048
#define LK 2048
#define DIM 1024
#define NEG_INF -1e10f

// 4 waves/block; each wave owns 4 q-rows fully in registers.
// Lane l owns elements d = j*256 + 4*l + {0..3} (float4) for j=0..3.
__global__ __launch_bounds__(256, 2) void attn_fp32_flash(
    const float* __restrict__ hidden,
    const float* __restrict__ keys,
    const float* __restrict__ values,
    const int* __restrict__ mask,
    float* __restrict__ out,
    int B)
{
    const int lane = threadIdx.x & 63;
    const int wave = threadIdx.x >> 6;
    const int blk  = blockIdx.x;
    const int b    = blk >> 7;                   // 128 blocks per batch
    const int q0   = (blk & 127) * 16 + wave * 4;

    float4 q[4][4];
    float4 o[4][4];
    float  m[4], s[4];

    const float4* hp = (const float4*)(hidden + ((size_t)b * LQ + q0) * DIM);
#pragma unroll
    for (int r = 0; r < 4; ++r) {
#pragma unroll
        for (int j = 0; j < 4; ++j) {
            q[r][j] = hp[r * 256 + j * 64 + lane];
            o[r][j] = make_float4(0.f, 0.f, 0.f, 0.f);
        }
        m[r] = -INFINITY;
        s[r] = 0.f;
    }

    const float4* kp = (const float4*)(keys   + (size_t)b * LK * DIM);
    const float4* vp = (const float4*)(values + (size_t)b * LK * DIM);
    const int*    mp = mask + b * LK;

    for (int k = 0; k < LK; ++k) {
        // ---- load K row (coalesced, 1KB/wave) ----
        float4 kv[4];
#pragma unroll
        for (int j = 0; j < 4; ++j) kv[j] = kp[k * 256 + j * 64 + lane];

        // ---- per-lane partial dots for 4 rows ----
        float sc[4];
#pragma unroll
        for (int r = 0; r < 4; ++r) {
            float p = 0.f;
#pragma unroll
            for (int j = 0; j < 4; ++j) {
                p += q[r][j].x * kv[j].x + q[r][j].y * kv[j].y +
                     q[r][j].z * kv[j].z + q[r][j].w * kv[j].w;
            }
            sc[r] = p;
        }

        // ---- wave-wide butterfly reduce (all lanes end with full sum) ----
#pragma unroll
        for (int r = 0; r < 4; ++r) {
#pragma unroll
            for (int off = 32; off > 0; off >>= 1)
                sc[r] += __shfl_xor(sc[r], off, 64);
        }

        const int mk = mp[k];

        // ---- load V row (reused by all 4 rows) ----
        float4 vv[4];
#pragma unroll
        for (int j = 0; j < 4; ++j) vv[j] = vp[k * 256 + j * 64 + lane];

        // ---- online softmax update ----
#pragma unroll
        for (int r = 0; r < 4; ++r) {
            float score = mk ? sc[r] : NEG_INF;
            if (score > m[r]) {                 // wave-uniform branch, rare
                float scale = __expf(m[r] - score);
                m[r] = score;
                s[r] *= scale;
#pragma unroll
                for (int j = 0; j < 4; ++j) {
                    o[r][j].x *= scale; o[r][j].y *= scale;
                    o[r][j].z *= scale; o[r][j].w *= scale;
                }
            }
            float e = __expf(score - m[r]);
            s[r] += e;
#pragma unroll
            for (int j = 0; j < 4; ++j) {
                o[r][j].x += e * vv[j].x; o[r][j].y += e * vv[j].y;
                o[r][j].z += e * vv[j].z; o[r][j].w += e * vv[j].w;
            }
        }
    }

    // ---- epilogue: normalize + coalesced float4 store ----
    float4* op = (float4*)(out + ((size_t)b * LQ + q0) * DIM);
#pragma unroll
    for (int r = 0; r < 4; ++r) {
        float inv = 1.f / s[r];
#pragma unroll
        for (int j = 0; j < 4; ++j) {
            float4 t = o[r][j];
            t.x *= inv; t.y *= inv; t.z *= inv; t.w *= inv;
            op[r * 256 + j * 64 + lane] = t;
        }
    }
}

extern "C" void kernel_launch(void* const* d_in, const int* in_sizes, int n_in,
                              void* d_out, int out_size, void* d_ws, size_t ws_size,
                              hipStream_t stream) {
    const float* hidden = (const float*)d_in[0];
    const float* keys   = (const float*)d_in[1];
    const float* values = (const float*)d_in[2];
    const int*   mask   = (const int*)d_in[3];
    float* out = (float*)d_out;

    const int B = in_sizes[3] / LK;              // 8
    const int blocks = B * (LQ / 16);            // 1024

    hipLaunchKernelGGL(attn_fp32_flash, dim3(blocks), dim3(256), 0, stream,
                       hidden, keys, values, mask, out, B);
}